// Round 4
// baseline (638.910 us; speedup 1.0000x reference)
//
#include <hip/hip_runtime.h>
#include <math.h>

#define CDIM 256
#define RBFD 16
#define NATOMS 10000

typedef float f32x4 __attribute__((ext_vector_type(4)));

__device__ __forceinline__ float dot4e(float4 a, f32x4 b) {
  return a.x * b.x + a.y * b.y + a.z * b.z + a.w * b.w;
}

// ---------------------------------------------------------------------------
// CSR build: histogram -> single-block exclusive scan -> scatter edge ids.
// ---------------------------------------------------------------------------
__global__ void hist_kernel(const int* __restrict__ eidx, int* __restrict__ counts,
                            int E) {
  const int i = blockIdx.x * blockDim.x + threadIdx.x;
  if (i < E) atomicAdd(&counts[eidx[i]], 1);
}

__global__ void scan_kernel(const int* __restrict__ counts,
                            int* __restrict__ offsets, int* __restrict__ cursor) {
  __shared__ int part[256];
  const int t = threadIdx.x;
  const int CH = (NATOMS + 255) / 256;  // 40
  const int base = t * CH;
  const int n = min(CH, max(0, NATOMS - base));
  int s = 0;
  for (int j = 0; j < n; ++j) s += counts[base + j];
  part[t] = s;
  __syncthreads();
  for (int off = 1; off < 256; off <<= 1) {
    int v = 0;
    if (t >= off) v = part[t - off];
    __syncthreads();
    part[t] += v;
    __syncthreads();
  }
  int run = part[t] - s;  // exclusive start for this chunk
  for (int j = 0; j < n; ++j) {
    offsets[base + j] = run;
    cursor[base + j] = run;
    run += counts[base + j];
  }
  if (t == 255) offsets[NATOMS] = part[255];
}

__global__ void scatter_kernel(const int* __restrict__ eidx,
                               int* __restrict__ cursor, int* __restrict__ elist,
                               int E) {
  const int i = blockIdx.x * blockDim.x + threadIdx.x;
  if (i < E) {
    const int a = eidx[i];
    const int pos = atomicAdd(&cursor[a], 1);
    elist[pos] = i;
  }
}

// ---------------------------------------------------------------------------
// Gather phase: one wave per atom. Lane l owns channels 4l..4l+3.
// acc[a][c] = sum_{e in bucket(a)} (b_rbf[c] + rbf[e]·w_rbf[c]) * x[e][c]
//
// R4 (hardened R3): per-wave LDS ring, depth 8, filled by global_load_lds.
//  - vmcnt counts ONLY glds: each slot region holds exactly 2 glds, fenced
//    by the surrounding asm memory clobbers, so at any consume the newer-op
//    floor is 14 glds. Wait vmcnt(12) (2 slack). Id loads are wave-uniform
//    (readfirstlane) so whether they go SMEM or VMEM the wait stays safe.
//  - prologue glds order pinned with sched_barrier(0) after each prefetch.
//  - asm outputs are early-clobber ("=&v") so ds_read destinations can never
//    alias the address inputs (R3 bug).
// ---------------------------------------------------------------------------
#define SLOT_BYTES 1280  // 1024 (x row) + 256 (rbf row area)
#define RING_DEPTH 8

__global__ __launch_bounds__(256) void gather_kernel(
    const float* __restrict__ x, const float* __restrict__ rbf,
    const int* __restrict__ elist, const int* __restrict__ offsets,
    const float* __restrict__ w_rbf, const float* __restrict__ b_rbf,
    float* __restrict__ acc) {
  __shared__ __align__(16) char ring[4 * RING_DEPTH * SLOT_BYTES];
  const int tid = threadIdx.x;
  const int lane = tid & 63;
  const int atom = (blockIdx.x * blockDim.x + tid) >> 6;
  if (atom >= NATOMS) return;
  const int wbase = (tid >> 6) * (RING_DEPTH * SLOT_BYTES);
  const int c0 = lane * 4;

  const int start = __builtin_amdgcn_readfirstlane(offsets[atom]);
  const int end = __builtin_amdgcn_readfirstlane(offsets[atom + 1]);

  // Hoist this lane's 4 rows of w_rbf (4x16 floats) + bias into registers.
  float4 wv[4][4];
  const float4 bb = *(const float4*)(b_rbf + c0);
#pragma unroll
  for (int j = 0; j < 4; ++j) {
    const float4* wr = (const float4*)(w_rbf + (size_t)(c0 + j) * RBFD);
    wv[j][0] = wr[0];
    wv[j][1] = wr[1];
    wv[j][2] = wr[2];
    wv[j][3] = wr[3];
  }

  if (end <= start) {  // empty bucket
    *(float4*)(acc + (size_t)atom * CDIM + c0) = make_float4(0.f, 0.f, 0.f, 0.f);
    return;
  }
  const int last = end - 1;

  // LDS raw offsets (addrspace(3) cast -> 32-bit LDS offset).
  const unsigned ring_off =
      (unsigned)(size_t)(__attribute__((address_space(3))) char*)ring;
  const unsigned vax = ring_off + wbase + lane * 16;  // x area, per-lane
  const unsigned vau = ring_off + wbase + 1024;       // rbf area, uniform

#define PREFETCH(J, eid)                                                      \
  {                                                                           \
    const int e_ = __builtin_amdgcn_readfirstlane(eid);                       \
    __builtin_amdgcn_global_load_lds(                                         \
        (const __attribute__((address_space(1))) void*)(x + (size_t)e_ * CDIM \
                                                        + lane * 4),          \
        (__attribute__((address_space(3))) void*)(ring + wbase +              \
                                                  (J)*SLOT_BYTES),            \
        16, 0, 0);                                                            \
    __builtin_amdgcn_global_load_lds(                                         \
        (const __attribute__((address_space(1))) void*)(                      \
            rbf + (size_t)e_ * RBFD + (lane & 15)),                           \
        (__attribute__((address_space(3))) void*)(ring + wbase +              \
                                                  (J)*SLOT_BYTES + 1024),     \
        4, 0, 0);                                                             \
  }

#define COMPUTE_BODY(sum)                                                     \
  {                                                                           \
    float4 f_;                                                                \
    f_.x = bb.x + dot4e(wv[0][0], r0) + dot4e(wv[0][1], r1) +                 \
           dot4e(wv[0][2], r2) + dot4e(wv[0][3], r3);                         \
    f_.y = bb.y + dot4e(wv[1][0], r0) + dot4e(wv[1][1], r1) +                 \
           dot4e(wv[1][2], r2) + dot4e(wv[1][3], r3);                         \
    f_.z = bb.z + dot4e(wv[2][0], r0) + dot4e(wv[2][1], r1) +                 \
           dot4e(wv[2][2], r2) + dot4e(wv[2][3], r3);                         \
    f_.w = bb.w + dot4e(wv[3][0], r0) + dot4e(wv[3][1], r1) +                 \
           dot4e(wv[3][2], r2) + dot4e(wv[3][3], r3);                         \
    sum.x += f_.x * xv.x;                                                     \
    sum.y += f_.y * xv.y;                                                     \
    sum.z += f_.z * xv.z;                                                     \
    sum.w += f_.w * xv.w;                                                     \
  }

  // Consume slot J in steady state (counted vmcnt keeps pipeline deep).
#define CONSUME(J, sum)                                                       \
  {                                                                           \
    f32x4 xv, r0, r1, r2, r3;                                                 \
    const unsigned ax_ = vax + (J)*SLOT_BYTES;                                \
    const unsigned au_ = vau + (J)*SLOT_BYTES;                                \
    asm volatile(                                                             \
        "s_waitcnt vmcnt(12)\n\t"                                             \
        "ds_read_b128 %0, %5\n\t"                                             \
        "ds_read_b128 %1, %6\n\t"                                             \
        "ds_read_b128 %2, %6 offset:16\n\t"                                   \
        "ds_read_b128 %3, %6 offset:32\n\t"                                   \
        "ds_read_b128 %4, %6 offset:48\n\t"                                   \
        "s_waitcnt lgkmcnt(0)"                                                \
        : "=&v"(xv), "=&v"(r0), "=&v"(r1), "=&v"(r2), "=&v"(r3)               \
        : "v"(ax_), "v"(au_)                                                  \
        : "memory");                                                          \
    __builtin_amdgcn_sched_barrier(0);                                        \
    COMPUTE_BODY(sum)                                                         \
  }

  // Consume with no vmcnt wait (epilogue: already drained).
#define CONSUME_NW(J, sum)                                                    \
  {                                                                           \
    f32x4 xv, r0, r1, r2, r3;                                                 \
    const unsigned ax_ = vax + (J)*SLOT_BYTES;                                \
    const unsigned au_ = vau + (J)*SLOT_BYTES;                                \
    asm volatile(                                                             \
        "ds_read_b128 %0, %5\n\t"                                             \
        "ds_read_b128 %1, %6\n\t"                                             \
        "ds_read_b128 %2, %6 offset:16\n\t"                                   \
        "ds_read_b128 %3, %6 offset:32\n\t"                                   \
        "ds_read_b128 %4, %6 offset:48\n\t"                                   \
        "s_waitcnt lgkmcnt(0)"                                                \
        : "=&v"(xv), "=&v"(r0), "=&v"(r1), "=&v"(r2), "=&v"(r3)               \
        : "v"(ax_), "v"(au_)                                                  \
        : "memory");                                                          \
    __builtin_amdgcn_sched_barrier(0);                                        \
    COMPUTE_BODY(sum)                                                         \
  }

  float4 sumA = make_float4(0.f, 0.f, 0.f, 0.f);
  float4 sumB = make_float4(0.f, 0.f, 0.f, 0.f);

  // Window-0 ids (uniform indices -> scalar loads; issued before any glds).
  int id0[RING_DEPTH];
#pragma unroll
  for (int j = 0; j < RING_DEPTH; ++j)
    id0[j] = __builtin_amdgcn_readfirstlane(elist[min(start + j, last)]);

  int idr[RING_DEPTH];  // id ring: ids for the NEXT window
  // Prologue: pin gld issue order (slot 0 oldest) with sched_barriers.
#pragma unroll
  for (int j = 0; j < RING_DEPTH; ++j) {
    PREFETCH(j, id0[j])
    __builtin_amdgcn_sched_barrier(0);
    idr[j] = __builtin_amdgcn_readfirstlane(
        elist[min(start + RING_DEPTH + j, last)]);
  }

  int i = start;
  for (; i + RING_DEPTH <= end; i += RING_DEPTH) {
#pragma unroll
    for (int j = 0; j < RING_DEPTH; ++j) {
      if (j & 1) {
        CONSUME(j, sumB)
      } else {
        CONSUME(j, sumA)
      }
      PREFETCH(j, idr[j])
      __builtin_amdgcn_sched_barrier(0);
      idr[j] = __builtin_amdgcn_readfirstlane(
          elist[min(i + 2 * RING_DEPTH + j, last)]);
    }
  }

  // Epilogue: drain once, consume the 0..7 remaining real edges.
  asm volatile("s_waitcnt vmcnt(0)" ::: "memory");
  const int rem = end - i;
#pragma unroll
  for (int j = 0; j < RING_DEPTH; ++j) {
    if (j < rem) {
      if (j & 1) {
        CONSUME_NW(j, sumB)
      } else {
        CONSUME_NW(j, sumA)
      }
    }
  }

#undef PREFETCH
#undef COMPUTE_BODY
#undef CONSUME
#undef CONSUME_NW

  float4 sum;
  sum.x = sumA.x + sumB.x;
  sum.y = sumA.y + sumB.y;
  sum.z = sumA.z + sumB.z;
  sum.w = sumA.w + sumB.w;
  *(float4*)(acc + (size_t)atom * CDIM + c0) = sum;
}

// ---------------------------------------------------------------------------
// Transpose w1, w2 (256x256) into k-major layout.
// ---------------------------------------------------------------------------
__global__ void transpose_kernel(const float* __restrict__ w1,
                                 const float* __restrict__ w2,
                                 float* __restrict__ w1T,
                                 float* __restrict__ w2T) {
  __shared__ float tile[32][33];
  const float* src = blockIdx.z ? w2 : w1;
  float* dst = blockIdx.z ? w2T : w1T;
  const int bx = blockIdx.x * 32;
  const int by = blockIdx.y * 32;
  const int tx = threadIdx.x, ty = threadIdx.y;  // (32, 8)
#pragma unroll
  for (int i = 0; i < 32; i += 8)
    tile[ty + i][tx] = src[(size_t)(by + ty + i) * CDIM + bx + tx];
  __syncthreads();
#pragma unroll
  for (int i = 0; i < 32; i += 8)
    dst[(size_t)(bx + ty + i) * CDIM + by + tx] = tile[tx][ty + i];
}

// ---------------------------------------------------------------------------
// Fused per-atom MLP. Block = 256 threads, 32 atoms. Thread tile = 4 atoms x
// 8 channels, channels {4tc..4tc+3} and {128+4tc..128+4tc+3} so WK
// ds_read_b128s are lane-consecutive (conflict-free).
// ---------------------------------------------------------------------------
__global__ __launch_bounds__(256, 2) void mlp_kernel(
    const float* __restrict__ hin, const float* __restrict__ w1T,
    const float* __restrict__ b1, const float* __restrict__ w2T,
    const float* __restrict__ b2, const float* __restrict__ w3,
    const float* __restrict__ b3, float* __restrict__ out, int natoms) {
  __shared__ float H[32 * 256];   // [atom][k]
  __shared__ float WK[32 * 256];  // [k_local][c_out]; reused as reduce buffer
  const int tid = threadIdx.x;
  const int tc = tid & 31;
  const int ta = tid >> 5;
  const int a0 = blockIdx.x * 32;
  const int cA = tc * 4;        // channels cA..cA+3
  const int cB = 128 + tc * 4;  // channels cB..cB+3

  // Stage H (zero-pad invalid atoms in last block).
  {
    const float4* src = (const float4*)hin + (size_t)a0 * 64;
    float4* Hv = (float4*)H;
#pragma unroll
    for (int i = 0; i < 8; ++i) {
      const int idx = tid + i * 256;  // 0..2047
      const int ga = a0 + (idx >> 6);
      Hv[idx] = (ga < natoms) ? src[idx] : make_float4(0.f, 0.f, 0.f, 0.f);
    }
  }

  float s[4][8];  // post-silu activations of current layer

#pragma unroll 1
  for (int layer = 0; layer < 2; ++layer) {
    const float* wT = (layer == 0) ? w1T : w2T;
    const float* bias = (layer == 0) ? b1 : b2;
    float r[4][8];
    const float4 bA = *(const float4*)(bias + cA);
    const float4 bB = *(const float4*)(bias + cB);
#pragma unroll
    for (int a = 0; a < 4; ++a) {
      r[a][0] = bA.x; r[a][1] = bA.y; r[a][2] = bA.z; r[a][3] = bA.w;
      r[a][4] = bB.x; r[a][5] = bB.y; r[a][6] = bB.z; r[a][7] = bB.w;
    }

    for (int k0 = 0; k0 < 256; k0 += 32) {
      __syncthreads();  // previous chunk fully consumed
      {
        const float4* wsrc = (const float4*)(wT + (size_t)k0 * CDIM);
        float4* WKv = (float4*)WK;
#pragma unroll
        for (int i = 0; i < 8; ++i) WKv[tid + i * 256] = wsrc[tid + i * 256];
      }
      __syncthreads();

#pragma unroll
      for (int kk = 0; kk < 32; kk += 4) {
        float4 ha[4];
#pragma unroll
        for (int a = 0; a < 4; ++a)
          ha[a] = *(const float4*)&H[(ta * 4 + a) * 256 + k0 + kk];
#pragma unroll
        for (int u = 0; u < 4; ++u) {
          const float4 w0 = *(const float4*)&WK[(kk + u) * 256 + cA];
          const float4 w1v = *(const float4*)&WK[(kk + u) * 256 + cB];
#pragma unroll
          for (int a = 0; a < 4; ++a) {
            const float hv = (u == 0) ? ha[a].x
                           : (u == 1) ? ha[a].y
                           : (u == 2) ? ha[a].z : ha[a].w;
            r[a][0] += hv * w0.x;  r[a][1] += hv * w0.y;
            r[a][2] += hv * w0.z;  r[a][3] += hv * w0.w;
            r[a][4] += hv * w1v.x; r[a][5] += hv * w1v.y;
            r[a][6] += hv * w1v.z; r[a][7] += hv * w1v.w;
          }
        }
      }
    }

    // SiLU
#pragma unroll
    for (int a = 0; a < 4; ++a)
#pragma unroll
      for (int j = 0; j < 8; ++j) {
        const float v = r[a][j];
        s[a][j] = v / (1.0f + __expf(-v));
      }

    if (layer == 0) {
      __syncthreads();  // all H reads of layer 1 done
#pragma unroll
      for (int a = 0; a < 4; ++a) {
        *(float4*)&H[(ta * 4 + a) * 256 + cA] =
            make_float4(s[a][0], s[a][1], s[a][2], s[a][3]);
        *(float4*)&H[(ta * 4 + a) * 256 + cB] =
            make_float4(s[a][4], s[a][5], s[a][6], s[a][7]);
      }
    }
  }

  // Layer 3: per-atom dot with w3, reduce across the 32 channel groups.
  const float4 w3a = *(const float4*)(w3 + cA);
  const float4 w3b = *(const float4*)(w3 + cB);
  float part[4];
#pragma unroll
  for (int a = 0; a < 4; ++a) {
    part[a] = s[a][0] * w3a.x + s[a][1] * w3a.y + s[a][2] * w3a.z +
              s[a][3] * w3a.w + s[a][4] * w3b.x + s[a][5] * w3b.y +
              s[a][6] * w3b.z + s[a][7] * w3b.w;
  }
  __syncthreads();  // WK reads done; reuse as reduce buffer [32][33]
  float* red = WK;
#pragma unroll
  for (int a = 0; a < 4; ++a) red[(ta * 4 + a) * 33 + tc] = part[a];
  __syncthreads();
  if (tid < 32) {
    float sum = 0.f;
#pragma unroll
    for (int j = 0; j < 32; ++j) sum += red[tid * 33 + j];
    const int ga = a0 + tid;
    if (ga < natoms) out[ga] = sum + b3[0];
  }
}

extern "C" void kernel_launch(void* const* d_in, const int* in_sizes, int n_in,
                              void* d_out, int out_size, void* d_ws,
                              size_t ws_size, hipStream_t stream) {
  const float* x = (const float*)d_in[0];
  const float* rbf = (const float*)d_in[1];
  const int* eidx = (const int*)d_in[3];
  const float* w_rbf = (const float*)d_in[4];
  const float* b_rbf = (const float*)d_in[5];
  const float* w1 = (const float*)d_in[6];
  const float* b1 = (const float*)d_in[7];
  const float* w2 = (const float*)d_in[8];
  const float* b2 = (const float*)d_in[9];
  const float* w3 = (const float*)d_in[10];
  const float* b3 = (const float*)d_in[11];
  float* out = (float*)d_out;
  const int E = in_sizes[0] / CDIM;

  // Workspace layout.
  char* p = (char*)d_ws;
  float* acc = (float*)p;              p += (size_t)NATOMS * CDIM * sizeof(float);
  float* w1T = (float*)p;              p += CDIM * CDIM * sizeof(float);
  float* w2T = (float*)p;              p += CDIM * CDIM * sizeof(float);
  int* counts = (int*)p;               p += NATOMS * sizeof(int);
  int* offsets = (int*)p;              p += (NATOMS + 1) * sizeof(int);
  int* cursor = (int*)p;               p += NATOMS * sizeof(int);
  int* elist = (int*)p;                p += (size_t)E * sizeof(int);

  hipMemsetAsync(counts, 0, NATOMS * sizeof(int), stream);
  hist_kernel<<<(E + 255) / 256, 256, 0, stream>>>(eidx, counts, E);
  scan_kernel<<<1, 256, 0, stream>>>(counts, offsets, cursor);
  scatter_kernel<<<(E + 255) / 256, 256, 0, stream>>>(eidx, cursor, elist, E);
  transpose_kernel<<<dim3(8, 8, 2), dim3(32, 8), 0, stream>>>(w1, w2, w1T, w2T);
  gather_kernel<<<(NATOMS * 64 + 255) / 256, 256, 0, stream>>>(
      x, rbf, elist, offsets, w_rbf, b_rbf, acc);
  mlp_kernel<<<(NATOMS + 31) / 32, 256, 0, stream>>>(acc, w1T, b1, w2T, b2, w3,
                                                     b3, out, NATOMS);
}

// Round 5
// 627.095 us; speedup vs baseline: 1.0188x; 1.0188x over previous
//
#include <hip/hip_runtime.h>
#include <math.h>

#define CDIM 256
#define RBFD 16
#define NATOMS 10000

__device__ __forceinline__ float dot44(float4 a, float4 b) {
  return a.x * b.x + a.y * b.y + a.z * b.z + a.w * b.w;
}

// ---------------------------------------------------------------------------
// CSR build: histogram -> single-block exclusive scan -> scatter edge ids.
// ---------------------------------------------------------------------------
__global__ void hist_kernel(const int* __restrict__ eidx, int* __restrict__ counts,
                            int E) {
  const int i = blockIdx.x * blockDim.x + threadIdx.x;
  if (i < E) atomicAdd(&counts[eidx[i]], 1);
}

__global__ void scan_kernel(const int* __restrict__ counts,
                            int* __restrict__ offsets, int* __restrict__ cursor) {
  __shared__ int part[256];
  const int t = threadIdx.x;
  const int CH = (NATOMS + 255) / 256;  // 40
  const int base = t * CH;
  const int n = min(CH, max(0, NATOMS - base));
  int s = 0;
  for (int j = 0; j < n; ++j) s += counts[base + j];
  part[t] = s;
  __syncthreads();
  for (int off = 1; off < 256; off <<= 1) {
    int v = 0;
    if (t >= off) v = part[t - off];
    __syncthreads();
    part[t] += v;
    __syncthreads();
  }
  int run = part[t] - s;  // exclusive start for this chunk
  for (int j = 0; j < n; ++j) {
    offsets[base + j] = run;
    cursor[base + j] = run;
    run += counts[base + j];
  }
  if (t == 255) offsets[NATOMS] = part[255];
}

__global__ void scatter_kernel(const int* __restrict__ eidx,
                               int* __restrict__ cursor, int* __restrict__ elist,
                               int E) {
  const int i = blockIdx.x * blockDim.x + threadIdx.x;
  if (i < E) {
    const int a = eidx[i];
    const int pos = atomicAdd(&cursor[a], 1);
    elist[pos] = i;
  }
}

// ---------------------------------------------------------------------------
// Gather phase, R5: one BLOCK per atom, 4 waves; wave w owns channels
// [64w, 64w+64), lane = one channel. Per-lane state is tiny (filter row =
// 16 VGPR, stage = 17 VGPR), so a 3-stage rotating pipeline fits in ~85
// VGPR -> ~5 waves/SIMD (20 waves/CU), ~2x the in-flight memory of R2/R4.
// No LDS, no syncthreads, no inline asm: each wave stores its disjoint
// 256 B slice of acc directly (4 B/lane, coalesced).
//   acc[a][c] = sum_{e in bucket(a)} (b_rbf[c] + rbf[e]·w_rbf[c]) * x[e][c]
// ---------------------------------------------------------------------------
__global__ __launch_bounds__(256, 5) void gather_kernel(
    const float* __restrict__ x, const float* __restrict__ rbf,
    const int* __restrict__ elist, const int* __restrict__ offsets,
    const float* __restrict__ w_rbf, const float* __restrict__ b_rbf,
    float* __restrict__ acc) {
  const int tid = threadIdx.x;
  const int lane = tid & 63;
  const int w = tid >> 6;  // wave id within block: channel group
  const int atom = blockIdx.x;
  const int ch = w * 64 + lane;  // this lane's channel

  const int start = __builtin_amdgcn_readfirstlane(offsets[atom]);
  const int end = __builtin_amdgcn_readfirstlane(offsets[atom + 1]);

  // This lane's filter row of w_rbf (16 floats) + bias.
  float4 wv0, wv1, wv2, wv3;
  {
    const float4* wr = (const float4*)(w_rbf + (size_t)ch * RBFD);
    wv0 = wr[0];
    wv1 = wr[1];
    wv2 = wr[2];
    wv3 = wr[3];
  }
  const float bb = b_rbf[ch];

  if (end <= start) {  // empty bucket
    acc[(size_t)atom * CDIM + ch] = 0.f;
    return;
  }
  const int last = end - 1;

  float sumA = 0.f, sumB = 0.f, sumC = 0.f;

  // Rotating stage registers (x scalar + full rbf row per stage).
  float xA, xB, xC;
  float4 rA0, rA1, rA2, rA3;
  float4 rB0, rB1, rB2, rB3;
  float4 rC0, rC1, rC2, rC3;

#define LOADD(S, eid)                                                        \
  {                                                                          \
    x##S = x[(size_t)(eid)*CDIM + ch]; /* HBM-heavy stream first */          \
    const float4* q_ = (const float4*)(rbf + (size_t)(eid)*RBFD);            \
    r##S##0 = q_[0];                                                         \
    r##S##1 = q_[1];                                                         \
    r##S##2 = q_[2];                                                         \
    r##S##3 = q_[3];                                                         \
  }

#define COMPUTE(S, sum)                                                      \
  {                                                                          \
    const float f_ = bb + dot44(wv0, r##S##0) + dot44(wv1, r##S##1) +        \
                     dot44(wv2, r##S##2) + dot44(wv3, r##S##3);              \
    sum += f_ * x##S;                                                        \
  }

  // Prologue: ids for edges 0,1,2 resolved; data for edges 0,1 in flight.
  int idA = __builtin_amdgcn_readfirstlane(elist[start]);
  int idB = __builtin_amdgcn_readfirstlane(elist[min(start + 1, last)]);
  int idC = __builtin_amdgcn_readfirstlane(elist[min(start + 2, last)]);
  LOADD(A, idA)
  LOADD(B, idB)

  int i = start;
  for (; i + 3 <= end; i += 3) {
    idA = __builtin_amdgcn_readfirstlane(elist[min(i + 3, last)]);
    LOADD(C, idC)   // data for edge i+2 (id resolved last trip)
    COMPUTE(A, sumA)  // edge i
    idB = __builtin_amdgcn_readfirstlane(elist[min(i + 4, last)]);
    LOADD(A, idA)   // data for edge i+3
    COMPUTE(B, sumB)  // edge i+1
    idC = __builtin_amdgcn_readfirstlane(elist[min(i + 5, last)]);
    LOADD(B, idB)   // data for edge i+4
    COMPUTE(C, sumC)  // edge i+2
  }
  // Tail: 0..2 edges remain, already loaded in stages A,B.
  const int k = end - i;
  if (k >= 1) COMPUTE(A, sumA)
  if (k >= 2) COMPUTE(B, sumB)

#undef LOADD
#undef COMPUTE

  acc[(size_t)atom * CDIM + ch] = sumA + sumB + sumC;
}

// ---------------------------------------------------------------------------
// Transpose w1, w2 (256x256) into k-major layout.
// ---------------------------------------------------------------------------
__global__ void transpose_kernel(const float* __restrict__ w1,
                                 const float* __restrict__ w2,
                                 float* __restrict__ w1T,
                                 float* __restrict__ w2T) {
  __shared__ float tile[32][33];
  const float* src = blockIdx.z ? w2 : w1;
  float* dst = blockIdx.z ? w2T : w1T;
  const int bx = blockIdx.x * 32;
  const int by = blockIdx.y * 32;
  const int tx = threadIdx.x, ty = threadIdx.y;  // (32, 8)
#pragma unroll
  for (int i = 0; i < 32; i += 8)
    tile[ty + i][tx] = src[(size_t)(by + ty + i) * CDIM + bx + tx];
  __syncthreads();
#pragma unroll
  for (int i = 0; i < 32; i += 8)
    dst[(size_t)(bx + ty + i) * CDIM + by + tx] = tile[tx][ty + i];
}

// ---------------------------------------------------------------------------
// Fused per-atom MLP. Block = 256 threads, 32 atoms. Thread tile = 4 atoms x
// 8 channels, channels {4tc..4tc+3} and {128+4tc..128+4tc+3} so WK
// ds_read_b128s are lane-consecutive (conflict-free).
// ---------------------------------------------------------------------------
__global__ __launch_bounds__(256, 2) void mlp_kernel(
    const float* __restrict__ hin, const float* __restrict__ w1T,
    const float* __restrict__ b1, const float* __restrict__ w2T,
    const float* __restrict__ b2, const float* __restrict__ w3,
    const float* __restrict__ b3, float* __restrict__ out, int natoms) {
  __shared__ float H[32 * 256];   // [atom][k]
  __shared__ float WK[32 * 256];  // [k_local][c_out]; reused as reduce buffer
  const int tid = threadIdx.x;
  const int tc = tid & 31;
  const int ta = tid >> 5;
  const int a0 = blockIdx.x * 32;
  const int cA = tc * 4;        // channels cA..cA+3
  const int cB = 128 + tc * 4;  // channels cB..cB+3

  // Stage H (zero-pad invalid atoms in last block).
  {
    const float4* src = (const float4*)hin + (size_t)a0 * 64;
    float4* Hv = (float4*)H;
#pragma unroll
    for (int i = 0; i < 8; ++i) {
      const int idx = tid + i * 256;  // 0..2047
      const int ga = a0 + (idx >> 6);
      Hv[idx] = (ga < natoms) ? src[idx] : make_float4(0.f, 0.f, 0.f, 0.f);
    }
  }

  float s[4][8];  // post-silu activations of current layer

#pragma unroll 1
  for (int layer = 0; layer < 2; ++layer) {
    const float* wT = (layer == 0) ? w1T : w2T;
    const float* bias = (layer == 0) ? b1 : b2;
    float r[4][8];
    const float4 bA = *(const float4*)(bias + cA);
    const float4 bB = *(const float4*)(bias + cB);
#pragma unroll
    for (int a = 0; a < 4; ++a) {
      r[a][0] = bA.x; r[a][1] = bA.y; r[a][2] = bA.z; r[a][3] = bA.w;
      r[a][4] = bB.x; r[a][5] = bB.y; r[a][6] = bB.z; r[a][7] = bB.w;
    }

    for (int k0 = 0; k0 < 256; k0 += 32) {
      __syncthreads();  // previous chunk fully consumed
      {
        const float4* wsrc = (const float4*)(wT + (size_t)k0 * CDIM);
        float4* WKv = (float4*)WK;
#pragma unroll
        for (int i = 0; i < 8; ++i) WKv[tid + i * 256] = wsrc[tid + i * 256];
      }
      __syncthreads();

#pragma unroll
      for (int kk = 0; kk < 32; kk += 4) {
        float4 ha[4];
#pragma unroll
        for (int a = 0; a < 4; ++a)
          ha[a] = *(const float4*)&H[(ta * 4 + a) * 256 + k0 + kk];
#pragma unroll
        for (int u = 0; u < 4; ++u) {
          const float4 w0 = *(const float4*)&WK[(kk + u) * 256 + cA];
          const float4 w1v = *(const float4*)&WK[(kk + u) * 256 + cB];
#pragma unroll
          for (int a = 0; a < 4; ++a) {
            const float hv = (u == 0) ? ha[a].x
                           : (u == 1) ? ha[a].y
                           : (u == 2) ? ha[a].z : ha[a].w;
            r[a][0] += hv * w0.x;  r[a][1] += hv * w0.y;
            r[a][2] += hv * w0.z;  r[a][3] += hv * w0.w;
            r[a][4] += hv * w1v.x; r[a][5] += hv * w1v.y;
            r[a][6] += hv * w1v.z; r[a][7] += hv * w1v.w;
          }
        }
      }
    }

    // SiLU
#pragma unroll
    for (int a = 0; a < 4; ++a)
#pragma unroll
      for (int j = 0; j < 8; ++j) {
        const float v = r[a][j];
        s[a][j] = v / (1.0f + __expf(-v));
      }

    if (layer == 0) {
      __syncthreads();  // all H reads of layer 1 done
#pragma unroll
      for (int a = 0; a < 4; ++a) {
        *(float4*)&H[(ta * 4 + a) * 256 + cA] =
            make_float4(s[a][0], s[a][1], s[a][2], s[a][3]);
        *(float4*)&H[(ta * 4 + a) * 256 + cB] =
            make_float4(s[a][4], s[a][5], s[a][6], s[a][7]);
      }
    }
  }

  // Layer 3: per-atom dot with w3, reduce across the 32 channel groups.
  const float4 w3a = *(const float4*)(w3 + cA);
  const float4 w3b = *(const float4*)(w3 + cB);
  float part[4];
#pragma unroll
  for (int a = 0; a < 4; ++a) {
    part[a] = s[a][0] * w3a.x + s[a][1] * w3a.y + s[a][2] * w3a.z +
              s[a][3] * w3a.w + s[a][4] * w3b.x + s[a][5] * w3b.y +
              s[a][6] * w3b.z + s[a][7] * w3b.w;
  }
  __syncthreads();  // WK reads done; reuse as reduce buffer [32][33]
  float* red = WK;
#pragma unroll
  for (int a = 0; a < 4; ++a) red[(ta * 4 + a) * 33 + tc] = part[a];
  __syncthreads();
  if (tid < 32) {
    float sum = 0.f;
#pragma unroll
    for (int j = 0; j < 32; ++j) sum += red[tid * 33 + j];
    const int ga = a0 + tid;
    if (ga < natoms) out[ga] = sum + b3[0];
  }
}

extern "C" void kernel_launch(void* const* d_in, const int* in_sizes, int n_in,
                              void* d_out, int out_size, void* d_ws,
                              size_t ws_size, hipStream_t stream) {
  const float* x = (const float*)d_in[0];
  const float* rbf = (const float*)d_in[1];
  const int* eidx = (const int*)d_in[3];
  const float* w_rbf = (const float*)d_in[4];
  const float* b_rbf = (const float*)d_in[5];
  const float* w1 = (const float*)d_in[6];
  const float* b1 = (const float*)d_in[7];
  const float* w2 = (const float*)d_in[8];
  const float* b2 = (const float*)d_in[9];
  const float* w3 = (const float*)d_in[10];
  const float* b3 = (const float*)d_in[11];
  float* out = (float*)d_out;
  const int E = in_sizes[0] / CDIM;

  // Workspace layout.
  char* p = (char*)d_ws;
  float* acc = (float*)p;              p += (size_t)NATOMS * CDIM * sizeof(float);
  float* w1T = (float*)p;              p += CDIM * CDIM * sizeof(float);
  float* w2T = (float*)p;              p += CDIM * CDIM * sizeof(float);
  int* counts = (int*)p;               p += NATOMS * sizeof(int);
  int* offsets = (int*)p;              p += (NATOMS + 1) * sizeof(int);
  int* cursor = (int*)p;               p += NATOMS * sizeof(int);
  int* elist = (int*)p;                p += (size_t)E * sizeof(int);

  hipMemsetAsync(counts, 0, NATOMS * sizeof(int), stream);
  hist_kernel<<<(E + 255) / 256, 256, 0, stream>>>(eidx, counts, E);
  scan_kernel<<<1, 256, 0, stream>>>(counts, offsets, cursor);
  scatter_kernel<<<(E + 255) / 256, 256, 0, stream>>>(eidx, cursor, elist, E);
  transpose_kernel<<<dim3(8, 8, 2), dim3(32, 8), 0, stream>>>(w1, w2, w1T, w2T);
  gather_kernel<<<NATOMS, 256, 0, stream>>>(x, rbf, elist, offsets, w_rbf,
                                            b_rbf, acc);
  mlp_kernel<<<(NATOMS + 31) / 32, 256, 0, stream>>>(acc, w1T, b1, w2T, b2, w3,
                                                     b3, out, NATOMS);
}